// Round 5
// baseline (345.408 us; speedup 1.0000x reference)
//
#include <hip/hip_runtime.h>
#include <hip/hip_bf16.h>

typedef __bf16 bf16_t;
typedef __bf16 bf16x2 __attribute__((ext_vector_type(2)));
typedef __bf16 bf16x8 __attribute__((ext_vector_type(8)));
typedef float f32x4 __attribute__((ext_vector_type(4)));
typedef float f32x16 __attribute__((ext_vector_type(16)));
typedef int intx4 __attribute__((ext_vector_type(4)));
typedef unsigned int u32;
typedef unsigned long long u64;

#define S_LEN 2048
#define DM 1024
#define NH 16
#define DK 64
#define M_ROWS 4096
#define SCALE_LOG2E 0.1803368801111204f /* 0.125 * log2(e) */

// 64-col bf16 LDS tile: 8 chunks of 8 elems (16B); phys chunk = chunk ^ (row&7).
__device__ __forceinline__ int sw_off(int row, int col) {
  return row * 64 + ((((col >> 3) ^ row) & 7) << 3) + (col & 7);
}

__device__ __forceinline__ bf16x8 cvt8(const float4& a, const float4& b) {
  bf16x8 v;
  v[0] = (__bf16)a.x; v[1] = (__bf16)a.y; v[2] = (__bf16)a.z; v[3] = (__bf16)a.w;
  v[4] = (__bf16)b.x; v[5] = (__bf16)b.y; v[6] = (__bf16)b.z; v[7] = (__bf16)b.w;
  return v;
}

__device__ __forceinline__ void glds16(const bf16_t* g, bf16_t* l) {
  __builtin_amdgcn_global_load_lds(
      (const __attribute__((address_space(1))) void*)g,
      (__attribute__((address_space(3))) void*)l, 16, 0, 0);
}

// pack two f32 -> u32 of 2 bf16 (lo = first)
__device__ __forceinline__ int pk2(float lo, float hi) {
  bf16x2 t;
  t[0] = (__bf16)lo;
  t[1] = (__bf16)hi;
  return __builtin_bit_cast(int, t);
}

// mask int32 [B,1,S,S] -> row-packed u64 via wave ballot:
// mb[(b*32+kw)*2048 + q], bit i = mask[b][q][kw*64+i]
__global__ __launch_bounds__(256) void pack_mask(
    const int* __restrict__ mask, u64* __restrict__ mb)
{
  const int wgl = blockIdx.x * 4 + (threadIdx.x >> 6);  // word idx: b(1)|kw(5)|q(11)
  const int lane = threadIdx.x & 63;
  const int q = wgl & 2047;
  const int kw = (wgl >> 11) & 31;
  const int b = wgl >> 16;
  const int val = mask[((size_t)(b * S_LEN + q)) * S_LEN + kw * 64 + lane];
  const u64 bits = __ballot(val != 0);
  if (lane == 0) mb[wgl] = bits;
}

// q,k,v fp32 -> Xb bf16 [3][4096][1024]
__global__ __launch_bounds__(256) void cvt_inputs(
    const float* __restrict__ q, const float* __restrict__ k,
    const float* __restrict__ v, bf16_t* __restrict__ Xb)
{
  const int z = blockIdx.y;
  const float* __restrict__ src = (z == 0) ? q : ((z == 1) ? k : v);
  const size_t idx = ((size_t)blockIdx.x * 256 + threadIdx.x) * 8;
  const float4 a = *(const float4*)&src[idx];
  const float4 b = *(const float4*)&src[idx + 4];
  *(bf16x8*)&Xb[(size_t)z * M_ROWS * DM + idx] = cvt8(a, b);
}

// W fp32 [k][n] -> Wt bf16 [n][k]  (z selects Wq/Wk/Wv/Wo)
__global__ __launch_bounds__(256) void transw_kernel(
    const float* __restrict__ Wq, const float* __restrict__ Wk,
    const float* __restrict__ Wv, const float* __restrict__ Wo,
    bf16_t* __restrict__ Wt)
{
  const int z = blockIdx.z;
  const float* __restrict__ W = (z == 0) ? Wq : ((z == 1) ? Wk : ((z == 2) ? Wv : Wo));
  bf16_t* __restrict__ out = Wt + (size_t)z * DM * DM;
  __shared__ float tile[64][65];
  const int tx = threadIdx.x & 31, ty = threadIdx.x >> 5;
  const int k0 = blockIdx.x * 64, n0 = blockIdx.y * 64;
  #pragma unroll
  for (int j = 0; j < 8; ++j) {
    const float2 v = *(const float2*)&W[(size_t)(k0 + ty + 8 * j) * DM + n0 + tx * 2];
    tile[ty + 8 * j][tx * 2] = v.x;
    tile[ty + 8 * j][tx * 2 + 1] = v.y;
  }
  __syncthreads();
  #pragma unroll
  for (int j = 0; j < 8; ++j) {
    const int a = ty + 8 * j;
    bf16x2 p;
    p[0] = (__bf16)tile[tx * 2][a];
    p[1] = (__bf16)tile[tx * 2 + 1][a];
    *(bf16x2*)&out[(size_t)(n0 + a) * DM + k0 + tx * 2] = p;
  }
}

// m97-style 128x128 BK=32 BT-GEMM: C = (A[4096xK] @ Bt^T + bias) * scale
__device__ __forceinline__ void gemm128_body(
    const bf16_t* __restrict__ A, const bf16_t* __restrict__ Bt,
    const float* __restrict__ bias, const float scale,
    bf16_t* __restrict__ outb, float* __restrict__ outf)
{
  __shared__ __align__(16) bf16_t As[128 * 32];
  __shared__ __align__(16) bf16_t Bs[128 * 32];
  const int t = threadIdx.x, w = t >> 6, L = t & 63, quad = L >> 4, l16 = L & 15;
  const int m0 = blockIdx.x * 128, n0 = blockIdx.y * 128;
  const int mb = 64 * (w & 1), nb = 64 * (w >> 1);
  const int rowS = t >> 2, subS = (t & 3) * 8;

  f32x4 acc[4][4] = {};
  for (int k0 = 0; k0 < DM; k0 += 32) {
    __syncthreads();
    glds16(&A[(size_t)(m0 + rowS) * DM + k0 + subS],        &As[t * 8]);
    glds16(&A[(size_t)(m0 + 64 + rowS) * DM + k0 + subS],   &As[2048 + t * 8]);
    glds16(&Bt[(size_t)(n0 + rowS) * DM + k0 + subS],       &Bs[t * 8]);
    glds16(&Bt[(size_t)(n0 + 64 + rowS) * DM + k0 + subS],  &Bs[2048 + t * 8]);
    __syncthreads();
    bf16x8 af[4], bfr[4];
    #pragma unroll
    for (int mt = 0; mt < 4; ++mt)
      af[mt] = *(const bf16x8*)&As[(mb + 16 * mt + l16) * 32 + quad * 8];
    #pragma unroll
    for (int ct = 0; ct < 4; ++ct)
      bfr[ct] = *(const bf16x8*)&Bs[(nb + 16 * ct + l16) * 32 + quad * 8];
    #pragma unroll
    for (int mt = 0; mt < 4; ++mt)
      #pragma unroll
      for (int ct = 0; ct < 4; ++ct)
        acc[mt][ct] = __builtin_amdgcn_mfma_f32_16x16x32_bf16(af[mt], bfr[ct], acc[mt][ct], 0, 0, 0);
  }
  #pragma unroll
  for (int mt = 0; mt < 4; ++mt)
    #pragma unroll
    for (int ct = 0; ct < 4; ++ct)
      #pragma unroll
      for (int r = 0; r < 4; ++r) {
        const int row = m0 + mb + 16 * mt + quad * 4 + r;
        const int n = n0 + nb + 16 * ct + l16;
        const float val = (acc[mt][ct][r] + bias[n]) * scale;
        if (outb) outb[(size_t)row * DM + n] = (__bf16)val;
        else      outf[(size_t)row * DM + n] = val;
      }
}

__global__ __launch_bounds__(256) void gemm_qkv(
    const bf16_t* __restrict__ Xb, const bf16_t* __restrict__ Wt,
    const float* __restrict__ bq, const float* __restrict__ bk,
    const float* __restrict__ bv, bf16_t* __restrict__ QKVb)
{
  const int z = blockIdx.z;
  // Q slice pre-scaled by 0.125*log2(e): attn then computes exp2(QK) directly.
  gemm128_body(Xb + (size_t)z * M_ROWS * DM, Wt + (size_t)z * DM * DM,
               (z == 0) ? bq : ((z == 1) ? bk : bv),
               (z == 0) ? SCALE_LOG2E : 1.0f,
               QKVb + (size_t)z * M_ROWS * DM, nullptr);
}

__global__ __launch_bounds__(256) void gemm_out(
    const bf16_t* __restrict__ ctx, const bf16_t* __restrict__ Wto,
    const float* __restrict__ bo, float* __restrict__ out)
{
  gemm128_body(ctx, Wto, bo, 1.0f, nullptr, out);
}

// Vb [4096][1024] (head cols) -> Vtw [bh][dv=64][key=2048]
__global__ __launch_bounds__(256) void transpV(
    const bf16_t* __restrict__ Vb, bf16_t* __restrict__ Vtw)
{
  __shared__ bf16_t Tr[64 * 72];
  const int t = threadIdx.x;
  const int key0 = blockIdx.x * 64;
  const int bh = blockIdx.y, b = bh >> 4, h = bh & 15;
  const int r = t >> 2, c = (t & 3) * 16;
  const bf16_t* src = &Vb[(size_t)(b * S_LEN + key0 + r) * DM + h * DK + c];
  const bf16x8 v0 = *(const bf16x8*)src;
  const bf16x8 v1 = *(const bf16x8*)(src + 8);
  #pragma unroll
  for (int j = 0; j < 8; ++j) {
    Tr[r * 72 + c + j] = v0[j];
    Tr[r * 72 + c + 8 + j] = v1[j];
  }
  __syncthreads();
  const int dv = t >> 2, kc = (t & 3) * 16;
  bf16_t ov[16];
  #pragma unroll
  for (int j = 0; j < 16; ++j) ov[j] = Tr[(kc + j) * 72 + dv];
  bf16_t* dst = &Vtw[((size_t)bh * DK + dv) * S_LEN + key0 + kc];
  *(bf16x8*)dst = *(bf16x8*)&ov[0];
  *(bf16x8*)(dst + 8) = *(bf16x8*)&ov[8];
}

// Flash attention, BARRIER-FREE inner loop:
// K/V per (b,h) is 256KB each -> L2-resident. Fragments are gathered DIRECTLY
// from global into registers (per-lane base + imm offsets); no K/V LDS staging,
// no in-loop __syncthreads, no vmcnt drains — waves are fully independent
// (m233: the 2-phase stage+drain+barrier structure is ~70% overhead; R1-R4
// tweaks inside that structure were all null).
// Softmax: Q pre-scaled, p = exp2(sacc), mask = sign-extend AND, denominator
// on the MFMA pipe via ones-fragment. 4 waves = 2x2 (qhalf x khalf) quadrants;
// khalf partials additive, combined once via LDS at the end.
__global__ __launch_bounds__(256, 2) void attn_kernel(
    const bf16_t* __restrict__ Qb, const bf16_t* __restrict__ Kb,
    const bf16_t* __restrict__ Vtw, const u64* __restrict__ mb,
    bf16_t* __restrict__ ctx)
{
  __shared__ __align__(16) bf16_t Qs[64 * 64];  // 8KB: Q stage, then epilogue store scratch
  __shared__ float Osc[2 * 2048 + 64];          // 16.25KB: khalf-combine scratch

  const int t = threadIdx.x, w = t >> 6, L = t & 63;
  const int l31 = L & 31, h5 = L >> 5;
  const int qhalf = w & 1, khalf = w >> 1;
  const int q0 = blockIdx.x * 64;
  const int bh = blockIdx.y, b = bh >> 4, h = bh & 15;
  const int sr = t >> 2, sc = (t & 3) * 16;

  // stage Q (64 rows x 64), swizzled
  {
    const bf16_t* s = &Qb[(size_t)(b * S_LEN + q0 + sr) * DM + h * DK + sc];
    *(bf16x8*)&Qs[sw_off(sr, sc)]     = *(const bf16x8*)s;
    *(bf16x8*)&Qs[sw_off(sr, sc + 8)] = *(const bf16x8*)(s + 8);
  }
  __syncthreads();

  // Q fragments -> registers (rows 32*qhalf..+32)
  bf16x8 qf[4];
  #pragma unroll
  for (int ks = 0; ks < 4; ++ks)
    qf[ks] = *(const bf16x8*)&Qs[sw_off(32 * qhalf + l31, ks * 16 + 8 * h5)];

  // ones A-fragment for the denominator MFMA
  bf16x8 onesf;
  #pragma unroll
  for (int i = 0; i < 8; ++i) onesf[i] = (__bf16)1.0f;

  // per-lane global fragment bases (advance per 64-key tile)
  // K frag (ks): row = kt*64 + khalf*32 + l31, col = h*64 + ks*16 + 8*h5
  const bf16_t* kb = &Kb[(size_t)(b * S_LEN + khalf * 32 + l31) * DM + h * DK + 8 * h5];
  // V frag (s4, ot): row dv = 32*ot + l31, col = kt*64 + s4*16 + 8*h5
  const bf16_t* vb0 = &Vtw[((size_t)bh * DK + l31) * S_LEN + 8 * h5];
  const bf16_t* vb1 = vb0 + (size_t)32 * S_LEN;

  const int qg = q0 + 32 * qhalf + l31;
  const u64* pm = &mb[(size_t)b * 32 * S_LEN + qg];

  f32x16 O[2] = {};
  f32x16 l_acc = {};
  const int msh = khalf ? 32 : 0;

  for (int kt = 0; kt < S_LEN / 64; ++kt) {
    const u64 mcur = *pm; pm += S_LEN;
    // K fragments: 4 x 16B gathers (imm offsets); issue all up front
    const bf16x8 kf0 = *(const bf16x8*)(kb + 0);
    const bf16x8 kf1 = *(const bf16x8*)(kb + 16);
    const bf16x8 kf2 = *(const bf16x8*)(kb + 32);
    const bf16x8 kf3 = *(const bf16x8*)(kb + 48);
    f32x16 sacc = {};
    __builtin_amdgcn_s_setprio(1);
    sacc = __builtin_amdgcn_mfma_f32_32x32x16_bf16(kf0, qf[0], sacc, 0, 0, 0);
    sacc = __builtin_amdgcn_mfma_f32_32x32x16_bf16(kf1, qf[1], sacc, 0, 0, 0);
    sacc = __builtin_amdgcn_mfma_f32_32x32x16_bf16(kf2, qf[2], sacc, 0, 0, 0);
    sacc = __builtin_amdgcn_mfma_f32_32x32x16_bf16(kf3, qf[3], sacc, 0, 0, 0);
    __builtin_amdgcn_s_setprio(0);

    const u32 mm = ((u32)(mcur >> msh)) >> (4 * h5);
    #pragma unroll
    for (int r = 0; r < 16; ++r) {
      const int cb = (r & 3) + 8 * (r >> 2);
      const u32 mr = (u32)(((int)(mm << (31 - cb))) >> 31);
      const float e = __builtin_exp2f(sacc[r]);
      sacc[r] = __builtin_bit_cast(float, __builtin_bit_cast(u32, e) & mr);
    }
    #pragma unroll
    for (int ss = 0; ss < 2; ++ss) {
      const int x0 = pk2(sacc[8 * ss + 0], sacc[8 * ss + 1]);
      const int x1 = pk2(sacc[8 * ss + 2], sacc[8 * ss + 3]);
      const int y0 = pk2(sacc[8 * ss + 4], sacc[8 * ss + 5]);
      const int y1 = pk2(sacc[8 * ss + 6], sacc[8 * ss + 7]);
      const auto r0 = __builtin_amdgcn_permlane32_swap(x0, y0, false, false);
      const auto r1 = __builtin_amdgcn_permlane32_swap(x1, y1, false, false);
      intx4 wv;
      wv[0] = r0[0]; wv[1] = r1[0]; wv[2] = r0[1]; wv[3] = r1[1];
      const bf16x8 pf = __builtin_bit_cast(bf16x8, wv);
      const int s4 = 2 * khalf + ss;  // 16-key slot within the 64-key tile
      const bf16x8 vf0 = *(const bf16x8*)(vb0 + s4 * 16);
      const bf16x8 vf1 = *(const bf16x8*)(vb1 + s4 * 16);
      __builtin_amdgcn_s_setprio(1);
      l_acc = __builtin_amdgcn_mfma_f32_32x32x16_bf16(onesf, pf, l_acc, 0, 0, 0);
      O[0] = __builtin_amdgcn_mfma_f32_32x32x16_bf16(vf0, pf, O[0], 0, 0, 0);
      O[1] = __builtin_amdgcn_mfma_f32_32x32x16_bf16(vf1, pf, O[1], 0, 0, 0);
      __builtin_amdgcn_s_setprio(0);
    }
    kb += (size_t)64 * DM;
    vb0 += 64;
    vb1 += 64;
  }

  // epilogue: combine khalf partials via LDS, normalize, store.
  // l_acc rows are identical: l_acc[0] = sum over this key-half for column q=l31.
  const float lw = l_acc[0];
  float* Lsc = Osc + 4096;  // [2 qhalf][32 q]
  if (khalf == 1) {
    #pragma unroll
    for (int ot = 0; ot < 2; ++ot)
      #pragma unroll
      for (int r = 0; r < 16; ++r) {
        const int dv = 32 * ot + (r & 3) + 8 * (r >> 2) + 4 * h5;
        Osc[qhalf * 2048 + dv * 32 + l31] = O[ot][r];
      }
    if (h5 == 0) Lsc[qhalf * 32 + l31] = lw;
  }
  __syncthreads();
  if (khalf == 0) {
    const float inv = 1.f / (lw + Lsc[qhalf * 32 + l31]);
    #pragma unroll
    for (int ot = 0; ot < 2; ++ot)
      #pragma unroll
      for (int r = 0; r < 16; ++r) {
        const int dv = 32 * ot + (r & 3) + 8 * (r >> 2) + 4 * h5;
        const float val = (O[ot][r] + Osc[qhalf * 2048 + dv * 32 + l31]) * inv;
        Qs[sw_off(32 * qhalf + l31, dv)] = (__bf16)val;
      }
    const int erow = 32 * qhalf + (L >> 1);
    const int ecol = (L & 1) * 32;
    bf16_t* dst = &ctx[(size_t)(b * S_LEN + q0 + erow) * DM + h * DK + ecol];
    #pragma unroll
    for (int c8 = 0; c8 < 4; ++c8)
      *(bf16x8*)(dst + 8 * c8) = *(const bf16x8*)&Qs[sw_off(erow, ecol + 8 * c8)];
  }
}

extern "C" void kernel_launch(void* const* d_in, const int* in_sizes, int n_in,
                              void* d_out, int out_size, void* d_ws, size_t ws_size,
                              hipStream_t stream) {
  const float* q  = (const float*)d_in[0];
  const float* k  = (const float*)d_in[1];
  const float* v  = (const float*)d_in[2];
  const int* mask = (const int*)d_in[3];
  const float* Wq = (const float*)d_in[4];
  const float* bq = (const float*)d_in[5];
  const float* Wk = (const float*)d_in[6];
  const float* bk = (const float*)d_in[7];
  const float* Wv = (const float*)d_in[8];
  const float* bv = (const float*)d_in[9];
  const float* Wo = (const float*)d_in[10];
  const float* bo = (const float*)d_in[11];
  float* out = (float*)d_out;

  const size_t SLICE = (size_t)M_ROWS * DM;  // 4M elems
  bf16_t* Xb   = (bf16_t*)d_ws;              // 3 slices (24 MB); reused below
  bf16_t* QKVb = Xb + 3 * SLICE;             // 3 slices (24 MB)
  bf16_t* Wt   = QKVb + 3 * SLICE;           // 4 MM (8 MB)
  u64* mbw     = (u64*)(Wt + (size_t)4 * DM * DM);  // 131072 u64 (1 MB)
  bf16_t* ctx  = Xb;                         // alias slice 0 (Xb dead after gemm_qkv)
  bf16_t* Vtw  = Xb + SLICE;                 // alias slice 1

  pack_mask<<<dim3(32768), dim3(256), 0, stream>>>(mask, mbw);
  cvt_inputs<<<dim3(2048, 3), dim3(256), 0, stream>>>(q, k, v, Xb);
  transw_kernel<<<dim3(16, 16, 4), dim3(256), 0, stream>>>(Wq, Wk, Wv, Wo, Wt);
  gemm_qkv<<<dim3(32, 8, 3), dim3(256), 0, stream>>>(Xb, Wt, bq, bk, bv, QKVb);
  transpV<<<dim3(32, 32), dim3(256), 0, stream>>>(QKVb + 2 * SLICE, Vtw);
  attn_kernel<<<dim3(32, 32), dim3(256), 0, stream>>>(QKVb, QKVb + SLICE, Vtw, mbw, ctx);
  gemm_out<<<dim3(32, 8), dim3(256), 0, stream>>>(ctx, Wt + (size_t)3 * DM * DM, bo, out);
}

// Round 6
// 280.211 us; speedup vs baseline: 1.2327x; 1.2327x over previous
//
#include <hip/hip_runtime.h>
#include <hip/hip_bf16.h>

typedef __bf16 bf16_t;
typedef __bf16 bf16x2 __attribute__((ext_vector_type(2)));
typedef __bf16 bf16x8 __attribute__((ext_vector_type(8)));
typedef float f32x4 __attribute__((ext_vector_type(4)));
typedef float f32x16 __attribute__((ext_vector_type(16)));
typedef int intx4 __attribute__((ext_vector_type(4)));
typedef unsigned int u32;
typedef unsigned long long u64;

#define S_LEN 2048
#define DM 1024
#define NH 16
#define DK 64
#define M_ROWS 4096
#define SCALE_LOG2E 0.1803368801111204f /* 0.125 * log2(e) */

// 64-col bf16 LDS tile: 8 chunks of 8 elems (16B); phys chunk = chunk ^ (row&7).
__device__ __forceinline__ int sw_off(int row, int col) {
  return row * 64 + ((((col >> 3) ^ row) & 7) << 3) + (col & 7);
}

__device__ __forceinline__ bf16x8 cvt8(const float4& a, const float4& b) {
  bf16x8 v;
  v[0] = (__bf16)a.x; v[1] = (__bf16)a.y; v[2] = (__bf16)a.z; v[3] = (__bf16)a.w;
  v[4] = (__bf16)b.x; v[5] = (__bf16)b.y; v[6] = (__bf16)b.z; v[7] = (__bf16)b.w;
  return v;
}

__device__ __forceinline__ void glds16(const bf16_t* g, bf16_t* l) {
  __builtin_amdgcn_global_load_lds(
      (const __attribute__((address_space(1))) void*)g,
      (__attribute__((address_space(3))) void*)l, 16, 0, 0);
}

// pack two f32 -> u32 of 2 bf16 (lo = first)
__device__ __forceinline__ int pk2(float lo, float hi) {
  bf16x2 t;
  t[0] = (__bf16)lo;
  t[1] = (__bf16)hi;
  return __builtin_bit_cast(int, t);
}

// mask int32 [B,1,S,S] -> row-packed u64 via wave ballot:
// mb[(b*32+kw)*2048 + q], bit i = mask[b][q][kw*64+i]
__global__ __launch_bounds__(256) void pack_mask(
    const int* __restrict__ mask, u64* __restrict__ mb)
{
  const int wgl = blockIdx.x * 4 + (threadIdx.x >> 6);  // word idx: b(1)|kw(5)|q(11)
  const int lane = threadIdx.x & 63;
  const int q = wgl & 2047;
  const int kw = (wgl >> 11) & 31;
  const int b = wgl >> 16;
  const int val = mask[((size_t)(b * S_LEN + q)) * S_LEN + kw * 64 + lane];
  const u64 bits = __ballot(val != 0);
  if (lane == 0) mb[wgl] = bits;
}

// q,k,v fp32 -> Xb bf16 [3][4096][1024]
__global__ __launch_bounds__(256) void cvt_inputs(
    const float* __restrict__ q, const float* __restrict__ k,
    const float* __restrict__ v, bf16_t* __restrict__ Xb)
{
  const int z = blockIdx.y;
  const float* __restrict__ src = (z == 0) ? q : ((z == 1) ? k : v);
  const size_t idx = ((size_t)blockIdx.x * 256 + threadIdx.x) * 8;
  const float4 a = *(const float4*)&src[idx];
  const float4 b = *(const float4*)&src[idx + 4];
  *(bf16x8*)&Xb[(size_t)z * M_ROWS * DM + idx] = cvt8(a, b);
}

// W fp32 [k][n] -> Wt bf16 [n][k]  (z selects Wq/Wk/Wv/Wo)
__global__ __launch_bounds__(256) void transw_kernel(
    const float* __restrict__ Wq, const float* __restrict__ Wk,
    const float* __restrict__ Wv, const float* __restrict__ Wo,
    bf16_t* __restrict__ Wt)
{
  const int z = blockIdx.z;
  const float* __restrict__ W = (z == 0) ? Wq : ((z == 1) ? Wk : ((z == 2) ? Wv : Wo));
  bf16_t* __restrict__ out = Wt + (size_t)z * DM * DM;
  __shared__ float tile[64][65];
  const int tx = threadIdx.x & 31, ty = threadIdx.x >> 5;
  const int k0 = blockIdx.x * 64, n0 = blockIdx.y * 64;
  #pragma unroll
  for (int j = 0; j < 8; ++j) {
    const float2 v = *(const float2*)&W[(size_t)(k0 + ty + 8 * j) * DM + n0 + tx * 2];
    tile[ty + 8 * j][tx * 2] = v.x;
    tile[ty + 8 * j][tx * 2 + 1] = v.y;
  }
  __syncthreads();
  #pragma unroll
  for (int j = 0; j < 8; ++j) {
    const int a = ty + 8 * j;
    bf16x2 p;
    p[0] = (__bf16)tile[tx * 2][a];
    p[1] = (__bf16)tile[tx * 2 + 1][a];
    *(bf16x2*)&out[(size_t)(n0 + a) * DM + k0 + tx * 2] = p;
  }
}

// m97-style 128x128 BK=32 BT-GEMM: C = (A[4096xK] @ Bt^T + bias) * scale
__device__ __forceinline__ void gemm128_body(
    const bf16_t* __restrict__ A, const bf16_t* __restrict__ Bt,
    const float* __restrict__ bias, const float scale,
    bf16_t* __restrict__ outb, float* __restrict__ outf)
{
  __shared__ __align__(16) bf16_t As[128 * 32];
  __shared__ __align__(16) bf16_t Bs[128 * 32];
  const int t = threadIdx.x, w = t >> 6, L = t & 63, quad = L >> 4, l16 = L & 15;
  const int m0 = blockIdx.x * 128, n0 = blockIdx.y * 128;
  const int mb = 64 * (w & 1), nb = 64 * (w >> 1);
  const int rowS = t >> 2, subS = (t & 3) * 8;

  f32x4 acc[4][4] = {};
  for (int k0 = 0; k0 < DM; k0 += 32) {
    __syncthreads();
    glds16(&A[(size_t)(m0 + rowS) * DM + k0 + subS],        &As[t * 8]);
    glds16(&A[(size_t)(m0 + 64 + rowS) * DM + k0 + subS],   &As[2048 + t * 8]);
    glds16(&Bt[(size_t)(n0 + rowS) * DM + k0 + subS],       &Bs[t * 8]);
    glds16(&Bt[(size_t)(n0 + 64 + rowS) * DM + k0 + subS],  &Bs[2048 + t * 8]);
    __syncthreads();
    bf16x8 af[4], bfr[4];
    #pragma unroll
    for (int mt = 0; mt < 4; ++mt)
      af[mt] = *(const bf16x8*)&As[(mb + 16 * mt + l16) * 32 + quad * 8];
    #pragma unroll
    for (int ct = 0; ct < 4; ++ct)
      bfr[ct] = *(const bf16x8*)&Bs[(nb + 16 * ct + l16) * 32 + quad * 8];
    #pragma unroll
    for (int mt = 0; mt < 4; ++mt)
      #pragma unroll
      for (int ct = 0; ct < 4; ++ct)
        acc[mt][ct] = __builtin_amdgcn_mfma_f32_16x16x32_bf16(af[mt], bfr[ct], acc[mt][ct], 0, 0, 0);
  }
  #pragma unroll
  for (int mt = 0; mt < 4; ++mt)
    #pragma unroll
    for (int ct = 0; ct < 4; ++ct)
      #pragma unroll
      for (int r = 0; r < 4; ++r) {
        const int row = m0 + mb + 16 * mt + quad * 4 + r;
        const int n = n0 + nb + 16 * ct + l16;
        const float val = (acc[mt][ct][r] + bias[n]) * scale;
        if (outb) outb[(size_t)row * DM + n] = (__bf16)val;
        else      outf[(size_t)row * DM + n] = val;
      }
}

__global__ __launch_bounds__(256) void gemm_qkv(
    const bf16_t* __restrict__ Xb, const bf16_t* __restrict__ Wt,
    const float* __restrict__ bq, const float* __restrict__ bk,
    const float* __restrict__ bv, bf16_t* __restrict__ QKVb)
{
  const int z = blockIdx.z;
  // Q slice pre-scaled by 0.125*log2(e): attn then computes exp2(QK) directly.
  gemm128_body(Xb + (size_t)z * M_ROWS * DM, Wt + (size_t)z * DM * DM,
               (z == 0) ? bq : ((z == 1) ? bk : bv),
               (z == 0) ? SCALE_LOG2E : 1.0f,
               QKVb + (size_t)z * M_ROWS * DM, nullptr);
}

__global__ __launch_bounds__(256) void gemm_out(
    const bf16_t* __restrict__ ctx, const bf16_t* __restrict__ Wto,
    const float* __restrict__ bo, float* __restrict__ out)
{
  gemm128_body(ctx, Wto, bo, 1.0f, nullptr, out);
}

// Vb [4096][1024] (head cols) -> Vtw [bh][dv=64][key=2048]
__global__ __launch_bounds__(256) void transpV(
    const bf16_t* __restrict__ Vb, bf16_t* __restrict__ Vtw)
{
  __shared__ bf16_t Tr[64 * 72];
  const int t = threadIdx.x;
  const int key0 = blockIdx.x * 64;
  const int bh = blockIdx.y, b = bh >> 4, h = bh & 15;
  const int r = t >> 2, c = (t & 3) * 16;
  const bf16_t* src = &Vb[(size_t)(b * S_LEN + key0 + r) * DM + h * DK + c];
  const bf16x8 v0 = *(const bf16x8*)src;
  const bf16x8 v1 = *(const bf16x8*)(src + 8);
  #pragma unroll
  for (int j = 0; j < 8; ++j) {
    Tr[r * 72 + c + j] = v0[j];
    Tr[r * 72 + c + 8 + j] = v1[j];
  }
  __syncthreads();
  const int dv = t >> 2, kc = (t & 3) * 16;
  bf16_t ov[16];
  #pragma unroll
  for (int j = 0; j < 16; ++j) ov[j] = Tr[(kc + j) * 72 + dv];
  bf16_t* dst = &Vtw[((size_t)bh * DK + dv) * S_LEN + key0 + kc];
  *(bf16x8*)dst = *(bf16x8*)&ov[0];
  *(bf16x8*)(dst + 8) = *(bf16x8*)&ov[8];
}

// Flash attention, QBLK=128 / 4 waves / full-64-key waves:
//  - staging+barriers amortized over 128 q-rows (2x less per key than QBLK=64);
//  - 16 MFMA per wave per barrier pair; no cross-wave combine (wave owns its q);
//  - glds-direct K/V staging w/ pre-swizzled source; R4's race-free dbuf loop
//    (stage next -> compute cur -> sync; load latency hides under ~900cy compute);
//  - Q fragments gathered once directly from global;
//  - softmax: prescaled Q, p = exp2(s), sign-extend-AND mask, l via VALU add
//    folded into mask step; epilogue wave-local (l = own + shfl_xor(32)).
// 32KB LDS, 2 blocks/CU (launch_bounds(256,2)), grid 512 = 2/CU.
__global__ __launch_bounds__(256, 2) void attn_kernel(
    const bf16_t* __restrict__ Qb, const bf16_t* __restrict__ Kb,
    const bf16_t* __restrict__ Vtw, const u64* __restrict__ mb,
    bf16_t* __restrict__ ctx)
{
  __shared__ __align__(16) bf16_t KVs[2][2][64 * 64];  // [buf][K,V][64x64] 32KB

  const int t = threadIdx.x, w = t >> 6, L = t & 63;
  const int l31 = L & 31, h5 = L >> 5;
  const int q0 = blockIdx.x * 128;
  const int bh = blockIdx.y, b = bh >> 4, h = bh & 15;

  // Q fragments: one-time direct gather (row q0+32w+l31; cols h*64+ks*16+8h5)
  bf16x8 qf[4];
  {
    const bf16_t* qsrc =
        &Qb[(size_t)(b * S_LEN + q0 + 32 * w + l31) * DM + h * DK + 8 * h5];
    #pragma unroll
    for (int ks = 0; ks < 4; ++ks) qf[ks] = *(const bf16x8*)(qsrc + 16 * ks);
  }

  // glds staging: wave w stages rows 16w..16w+16 of both K and V tiles.
  // dest elem = w*1024 + jj*512 + L*8 (linear); source col chunk = (L&7)^(L>>3)
  // pre-applies the sw_off XOR (row&7 == L>>3 for both jj).
  const int ch = (L & 7) ^ (L >> 3);
  const int row0 = 16 * w + (L >> 3);
  const int kofs0 = w * 1024 + L * 8, kofs1 = kofs0 + 512;
  const bf16_t* pK0 = &Kb[(size_t)(b * S_LEN + row0) * DM + h * DK + ch * 8];
  const bf16_t* pK1 = pK0 + (size_t)8 * DM;
  const bf16_t* pV0 = &Vtw[((size_t)bh * DK + row0) * S_LEN + ch * 8];
  const bf16_t* pV1 = pV0 + (size_t)8 * S_LEN;

  const u64* pm = &mb[(size_t)b * 32 * S_LEN + q0 + 32 * w + l31];

  auto stageKV = [&](int buf) {
    glds16(pK0, &KVs[buf][0][kofs0]);
    glds16(pK1, &KVs[buf][0][kofs1]);
    glds16(pV0, &KVs[buf][1][kofs0]);
    glds16(pV1, &KVs[buf][1][kofs1]);
    pK0 += (size_t)64 * DM; pK1 += (size_t)64 * DM;
    pV0 += 64; pV1 += 64;
  };

  f32x16 O[2] = {};
  float l_lane = 0.f;

  auto compute = [&](int buf, u64 mcur) {
    const bf16_t* __restrict__ Kc = &KVs[buf][0][0];
    const bf16_t* __restrict__ Vc = &KVs[buf][1][0];
    // S^T: keys [0,64) x q [32w, +32); lane col = q = l31, rows = crow(r,h5)
    f32x16 s0 = {}, s1 = {};
    __builtin_amdgcn_s_setprio(1);
    #pragma unroll
    for (int ks = 0; ks < 4; ++ks) {
      const bf16x8 kf0 = *(const bf16x8*)&Kc[sw_off(l31, ks * 16 + 8 * h5)];
      const bf16x8 kf1 = *(const bf16x8*)&Kc[sw_off(32 + l31, ks * 16 + 8 * h5)];
      s0 = __builtin_amdgcn_mfma_f32_32x32x16_bf16(kf0, qf[ks], s0, 0, 0, 0);
      s1 = __builtin_amdgcn_mfma_f32_32x32x16_bf16(kf1, qf[ks], s1, 0, 0, 0);
    }
    __builtin_amdgcn_s_setprio(0);
    #pragma unroll
    for (int nt = 0; nt < 2; ++nt) {
      const u32 mm = ((u32)(mcur >> (nt ? 32 : 0))) >> (4 * h5);
      const f32x16 sacc = nt ? s1 : s0;
      float p[16];
      #pragma unroll
      for (int r = 0; r < 16; ++r) {
        const int cb = (r & 3) + 8 * (r >> 2);
        const u32 mr = (u32)(((int)(mm << (31 - cb))) >> 31);
        const float e = __builtin_exp2f(sacc[r]);
        const float pv = __builtin_bit_cast(float, __builtin_bit_cast(u32, e) & mr);
        l_lane += pv;
        p[r] = pv;
      }
      #pragma unroll
      for (int ss = 0; ss < 2; ++ss) {
        const int x0 = pk2(p[8 * ss + 0], p[8 * ss + 1]);
        const int x1 = pk2(p[8 * ss + 2], p[8 * ss + 3]);
        const int y0 = pk2(p[8 * ss + 4], p[8 * ss + 5]);
        const int y1 = pk2(p[8 * ss + 6], p[8 * ss + 7]);
        const auto r0 = __builtin_amdgcn_permlane32_swap(x0, y0, false, false);
        const auto r1 = __builtin_amdgcn_permlane32_swap(x1, y1, false, false);
        intx4 wv;
        wv[0] = r0[0]; wv[1] = r1[0]; wv[2] = r0[1]; wv[3] = r1[1];
        const bf16x8 pf = __builtin_bit_cast(bf16x8, wv);
        const int s4 = 2 * nt + ss;  // 16-key slot within the 64-key tile
        const bf16x8 vf0 = *(const bf16x8*)&Vc[sw_off(l31, s4 * 16 + 8 * h5)];
        const bf16x8 vf1 = *(const bf16x8*)&Vc[sw_off(32 + l31, s4 * 16 + 8 * h5)];
        __builtin_amdgcn_s_setprio(1);
        O[0] = __builtin_amdgcn_mfma_f32_32x32x16_bf16(vf0, pf, O[0], 0, 0, 0);
        O[1] = __builtin_amdgcn_mfma_f32_32x32x16_bf16(vf1, pf, O[1], 0, 0, 0);
        __builtin_amdgcn_s_setprio(0);
      }
    }
  };

  // prologue: stage tile 0 into buf0
  stageKV(0);
  u64 mcur = *pm; pm += S_LEN;
  u64 mnext;
  __syncthreads();  // tile0 staged

  for (int kt = 0; kt < S_LEN / 64; kt += 2) {
    stageKV(1);                       // tile kt+1
    mnext = *pm; pm += S_LEN;
    compute(0, mcur);
    __syncthreads();                  // buf1 staged; all done reading buf0
    mcur = mnext;
    if (kt + 2 < S_LEN / 64) {
      stageKV(0);                     // tile kt+2
      mnext = *pm; pm += S_LEN;
    }
    compute(1, mcur);
    __syncthreads();
    mcur = mnext;
  }

  // epilogue (wave-local): l = own half + partner half; transpose via KVs scratch
  const float lsum = l_lane + __shfl_xor(l_lane, 32);
  const float inv = 1.f / lsum;
  bf16_t* sc = &KVs[0][0][0] + (size_t)w * 2048;  // wave-private 32x64 region
  #pragma unroll
  for (int ot = 0; ot < 2; ++ot)
    #pragma unroll
    for (int r = 0; r < 16; ++r) {
      const int dv = 32 * ot + (r & 3) + 8 * (r >> 2) + 4 * h5;
      sc[sw_off(l31, dv)] = (__bf16)(O[ot][r] * inv);
    }
  const int erow = L >> 1, ecol = (L & 1) * 32;
  bf16_t* dst = &ctx[(size_t)(b * S_LEN + q0 + 32 * w + erow) * DM + h * DK + ecol];
  #pragma unroll
  for (int c8 = 0; c8 < 4; ++c8)
    *(bf16x8*)(dst + 8 * c8) = *(const bf16x8*)&sc[sw_off(erow, ecol + 8 * c8)];
}

extern "C" void kernel_launch(void* const* d_in, const int* in_sizes, int n_in,
                              void* d_out, int out_size, void* d_ws, size_t ws_size,
                              hipStream_t stream) {
  const float* q  = (const float*)d_in[0];
  const float* k  = (const float*)d_in[1];
  const float* v  = (const float*)d_in[2];
  const int* mask = (const int*)d_in[3];
  const float* Wq = (const float*)d_in[4];
  const float* bq = (const float*)d_in[5];
  const float* Wk = (const float*)d_in[6];
  const float* bk = (const float*)d_in[7];
  const float* Wv = (const float*)d_in[8];
  const float* bv = (const float*)d_in[9];
  const float* Wo = (const float*)d_in[10];
  const float* bo = (const float*)d_in[11];
  float* out = (float*)d_out;

  const size_t SLICE = (size_t)M_ROWS * DM;  // 4M elems
  bf16_t* Xb   = (bf16_t*)d_ws;              // 3 slices (24 MB); reused below
  bf16_t* QKVb = Xb + 3 * SLICE;             // 3 slices (24 MB)
  bf16_t* Wt   = QKVb + 3 * SLICE;           // 4 MM (8 MB)
  u64* mbw     = (u64*)(Wt + (size_t)4 * DM * DM);  // 131072 u64 (1 MB)
  bf16_t* ctx  = Xb;                         // alias slice 0 (Xb dead after gemm_qkv)
  bf16_t* Vtw  = Xb + SLICE;                 // alias slice 1

  pack_mask<<<dim3(32768), dim3(256), 0, stream>>>(mask, mbw);
  cvt_inputs<<<dim3(2048, 3), dim3(256), 0, stream>>>(q, k, v, Xb);
  transw_kernel<<<dim3(16, 16, 4), dim3(256), 0, stream>>>(Wq, Wk, Wv, Wo, Wt);
  gemm_qkv<<<dim3(32, 8, 3), dim3(256), 0, stream>>>(Xb, Wt, bq, bk, bv, QKVb);
  transpV<<<dim3(32, 32), dim3(256), 0, stream>>>(QKVb + 2 * SLICE, Vtw);
  attn_kernel<<<dim3(16, 32), dim3(256), 0, stream>>>(QKVb, QKVb + SLICE, Vtw, mbw, ctx);
  gemm_out<<<dim3(32, 8), dim3(256), 0, stream>>>(ctx, Wt + (size_t)3 * DM * DM, bo, out);
}